// Round 12
// baseline (789.711 us; speedup 1.0000x reference)
//
#include <hip/hip_runtime.h>
#include <hip/hip_bf16.h>

typedef __hip_bfloat16 bf16;
typedef __attribute__((ext_vector_type(8))) short s8v;   // 8 bf16 = 16B
typedef __attribute__((ext_vector_type(4))) float f4v;

constexpr int S = 1024, CA = 768, CS = 384, CZ = 128, NHID = 1536;
constexpr int NBLK = 4, NHEAD = 16, DH = 48;
constexpr float EPS = 1e-5f;

#define DEV static __device__ __forceinline__

DEV float sigmoidf_(float x) { return 1.0f / (1.0f + __expf(-x)); }

DEV f4v mfma16(s8v a, s8v b, f4v c) {
  return __builtin_amdgcn_mfma_f32_16x16x32_bf16(a, b, c, 0, 0, 0);
}

union U8 { s8v s; bf16 h[8]; };
union U4 { uint2 u; bf16 h[4]; };

DEV float wred_sum(float v) {
#pragma unroll
  for (int o = 32; o; o >>= 1) v += __shfl_xor(v, o);
  return v;
}

// ================= prep_fat: transposes + bias prep + s-LN, one launch =================
struct PrepFatArgs {
  const float* tsrc[14];
  bf16* tdst[14];
  const float* tcs[14];
  long tdstZ[14];
  const float *ln_z_w, *ln_z_b, *wpb, *bq, *bsg_a, *bsg_t;
  bf16* W2T; float* bias2; float* biasQKVG; float* biasSG;
  const float* s_in; bf16* s_hat; bf16* s_bf;
};

__global__ __launch_bounds__(256) void prep_fat(PrepFatArgs a) {
  __shared__ __align__(16) float tile[1056];
  const int bid = blockIdx.x, t = threadIdx.x;
  if (bid < 32256) {  // transposes
    int ti, blk, x, y, K, N;
    if (bid < 6912) {
      const int lb = bid; ti = lb / 1152; const int r2 = lb % 1152;
      blk = r2 / 288; const int rem = r2 % 288; x = rem % 24; y = rem / 24; K = 384; N = 768;
    } else if (bid < 18432) {
      const int lb = bid - 6912; ti = 6 + lb / 2304; const int r2 = lb % 2304;
      blk = r2 / 576; const int rem = r2 % 576; x = rem % 24; y = rem / 24; K = 768; N = 768;
    } else if (bid < 27648) {
      const int lb = bid - 18432; ti = 11 + lb / 4608; const int r2 = lb % 4608;
      blk = r2 / 1152; const int rem = r2 % 1152; x = rem % 48; y = rem / 48; K = 768; N = 1536;
    } else {
      const int lb = bid - 27648; ti = 13; blk = lb / 1152;
      const int rem = lb % 1152; x = rem % 24; y = rem / 24; K = 1536; N = 768;
    }
    const float* src = a.tsrc[ti] + (size_t)blk * K * N;
    bf16* dst = a.tdst[ti] + (size_t)blk * a.tdstZ[ti];
    const float* cs = a.tcs[ti] ? (a.tcs[ti] + blk * CS) : nullptr;
    const int k0 = y * 32, n0 = x * 32, tx = t & 31, ty = t >> 5;
#pragma unroll
    for (int q = 0; q < 4; ++q) {
      const int k = k0 + ty + 8 * q;
      float v = src[(size_t)k * N + n0 + tx];
      if (cs) v *= cs[k];
      tile[(ty + 8 * q) * 33 + tx] = v;
    }
    __syncthreads();
#pragma unroll
    for (int q = 0; q < 4; ++q)
      dst[(size_t)(n0 + ty + 8 * q) * K + k0 + tx] = __float2bfloat16(tile[tx * 33 + ty + 8 * q]);
    return;
  }
  if (bid < 32305) {  // bias prep
    const int pid = bid - 32256;
    if (pid == 48) {
      for (int f = t; f < 64 * CZ; f += 256) {
        const int col = f >> 7, c = f & 127, b = col >> 4, h = col & 15;
        a.W2T[f] = __float2bfloat16(a.ln_z_w[b * CZ + c] * a.wpb[(b * CZ + c) * NHEAD + h]);
      }
      if (t < 64) {
        const int b = t >> 4, h = t & 15;
        float sum = 0.f;
        for (int c = 0; c < CZ; ++c)
          sum += a.ln_z_b[b * CZ + c] * a.wpb[(b * CZ + c) * NHEAD + h];
        a.bias2[t] = sum;
      }
      return;
    }
    const int g = pid * 256 + t;
    if (g < 4 * 3072) {
      const int b = g / 3072, c = g % 3072;
      a.biasQKVG[g] = (c < 768) ? a.bq[b * 768 + c] : 0.f;
    }
    if (g < 6144) {
      const int b = g / 1536, c = g % 1536;
      a.biasSG[g] = (c < 768) ? a.bsg_a[b * 768 + c] : a.bsg_t[b * 768 + c - 768];
    }
    return;
  }
  {  // rowln_s
    float* red = tile;
    const size_t row = bid - 32305;
    float4 v = make_float4(0.f, 0.f, 0.f, 0.f);
    if (t < CS / 4) v = ((const float4*)(a.s_in + row * CS))[t];
    float sum = v.x + v.y + v.z + v.w;
    float sq = v.x * v.x + v.y * v.y + v.z * v.z + v.w * v.w;
    sum = wred_sum(sum); sq = wred_sum(sq);
    const int wv = t >> 6;
    if ((t & 63) == 0) { red[2 * wv] = sum; red[2 * wv + 1] = sq; }
    __syncthreads();
    sum = red[0] + red[2] + red[4] + red[6];
    sq = red[1] + red[3] + red[5] + red[7];
    const float m = sum / CS;
    const float rstd = rsqrtf(sq / CS - m * m + EPS);
    if (t < CS / 4) {
      U4 oh, ob_;
      oh.h[0] = __float2bfloat16((v.x - m) * rstd); oh.h[1] = __float2bfloat16((v.y - m) * rstd);
      oh.h[2] = __float2bfloat16((v.z - m) * rstd); oh.h[3] = __float2bfloat16((v.w - m) * rstd);
      ob_.h[0] = __float2bfloat16(v.x); ob_.h[1] = __float2bfloat16(v.y);
      ob_.h[2] = __float2bfloat16(v.z); ob_.h[3] = __float2bfloat16(v.w);
      *(uint2*)(a.s_hat + row * CS + 4 * t) = oh.u;
      *(uint2*)(a.s_bf + row * CS + 4 * t) = ob_.u;
    }
  }
}

// ---------------- fused LN(a) + both adaLNs ----------------
__global__ __launch_bounds__(256) void ln_adaln2(const float* __restrict__ a,
                                                 const bf16* __restrict__ ada,
                                                 bf16* __restrict__ ah_attn,
                                                 bf16* __restrict__ ah_tr) {
  __shared__ float red[8];
  const int t = threadIdx.x;
  const size_t row = blockIdx.x;
  float4 v = make_float4(0.f, 0.f, 0.f, 0.f);
  if (t < 192) v = ((const float4*)(a + row * CA))[t];
  float sum = v.x + v.y + v.z + v.w;
  float sq = v.x * v.x + v.y * v.y + v.z * v.z + v.w * v.w;
  sum = wred_sum(sum); sq = wred_sum(sq);
  const int wv = t >> 6;
  if ((t & 63) == 0) { red[2 * wv] = sum; red[2 * wv + 1] = sq; }
  __syncthreads();
  sum = red[0] + red[2] + red[4] + red[6];
  sq = red[1] + red[3] + red[5] + red[7];
  const float m = sum / CA;
  const float rstd = rsqrtf(sq / CA - m * m + EPS);
  if (t < 192) {
    const float an[4] = {(v.x - m) * rstd, (v.y - m) * rstd, (v.z - m) * rstd, (v.w - m) * rstd};
    const bf16* ar = ada + row * 12288 + 4 * t;
    U4 g1, b1, g2, b2, o1, o2;
    g1.u = *(const uint2*)(ar);
    b1.u = *(const uint2*)(ar + 768);
    g2.u = *(const uint2*)(ar + 1536);
    b2.u = *(const uint2*)(ar + 2304);
#pragma unroll
    for (int j = 0; j < 4; ++j) {
      o1.h[j] = __float2bfloat16(sigmoidf_(__bfloat162float(g1.h[j])) * an[j] + __bfloat162float(b1.h[j]));
      o2.h[j] = __float2bfloat16(sigmoidf_(__bfloat162float(g2.h[j])) * an[j] + __bfloat162float(b2.h[j]));
    }
    *(uint2*)(ah_attn + row * CA + 4 * t) = o1.u;
    *(uint2*)(ah_tr + row * CA + 4 * t) = o2.u;
  }
}

// ---------------- zbias: LN(z)@W2T + bias2 + beta -> bf16 [64][S][S], MFMA ----------------
__global__ __launch_bounds__(256) void zbias_kernel(const float* __restrict__ z,
                                                    const float* __restrict__ beta,
                                                    const bf16* __restrict__ W2T,
                                                    const float* __restrict__ bias2,
                                                    bf16* __restrict__ bias_all) {
  __shared__ s8v zt8[64 * 16];
  __shared__ s8v w2s[64 * 16];
  __shared__ float betas[64][17];
  __shared__ float bias2s[64];
  __shared__ bf16 obuf[64][72];
  const int t = threadIdx.x;
  const int i = blockIdx.y, j0 = blockIdx.x * 64;
#pragma unroll
  for (int q = 0; q < 4; ++q) {
    const int u = q * 256 + t;
    const int row = u >> 4, sl = u & 15;
    w2s[row * 16 + (sl ^ (row & 7))] = *(const s8v*)(W2T + row * CZ + sl * 8);
  }
  if (t < 64) bias2s[t] = bias2[t];
  {
    const int j = t >> 2, h4 = t & 3;
    const float4 bv = *(const float4*)(beta + ((size_t)i * S + j0 + j) * NHEAD + 4 * h4);
    betas[j][4 * h4 + 0] = bv.x; betas[j][4 * h4 + 1] = bv.y;
    betas[j][4 * h4 + 2] = bv.z; betas[j][4 * h4 + 3] = bv.w;
  }
  {
    const int p = t >> 2, q = t & 3;
    const float* zr = z + ((size_t)i * S + j0 + p) * CZ + q * 32;
    float vals[32];
    float sum = 0.f, sq = 0.f;
#pragma unroll
    for (int k4 = 0; k4 < 8; ++k4) {
      const float4 xv = *(const float4*)(zr + 4 * k4);
      vals[4 * k4 + 0] = xv.x; vals[4 * k4 + 1] = xv.y;
      vals[4 * k4 + 2] = xv.z; vals[4 * k4 + 3] = xv.w;
      sum += xv.x + xv.y + xv.z + xv.w;
      sq += xv.x * xv.x + xv.y * xv.y + xv.z * xv.z + xv.w * xv.w;
    }
    sum += __shfl_xor(sum, 1); sum += __shfl_xor(sum, 2);
    sq += __shfl_xor(sq, 1); sq += __shfl_xor(sq, 2);
    const float m = sum / CZ;
    const float rstd = rsqrtf(sq / CZ - m * m + EPS);
#pragma unroll
    for (int u = 0; u < 4; ++u) {
      U8 pk;
#pragma unroll
      for (int e = 0; e < 8; ++e) pk.h[e] = __float2bfloat16((vals[8 * u + e] - m) * rstd);
      const int cu = 4 * q + u;
      zt8[p * 16 + (cu ^ (p & 7))] = pk.s;
    }
  }
  __syncthreads();
  const int lane = t & 63, wid = t >> 6;
  const int wr = wid >> 1, wc = wid & 1;
  const int ln = lane & 15, lq = lane >> 4;
  f4v acc[2][2] = {};
#pragma unroll
  for (int kk = 0; kk < 4; ++kk) {
    const int sl = (lq + 4 * kk) ^ (ln & 7);
    s8v a[2], b[2];
#pragma unroll
    for (int mi = 0; mi < 2; ++mi) a[mi] = zt8[(32 * wr + 16 * mi + ln) * 16 + sl];
#pragma unroll
    for (int ni = 0; ni < 2; ++ni) b[ni] = w2s[(32 * wc + 16 * ni + ln) * 16 + sl];
#pragma unroll
    for (int mi = 0; mi < 2; ++mi)
#pragma unroll
      for (int ni = 0; ni < 2; ++ni) acc[mi][ni] = mfma16(a[mi], b[ni], acc[mi][ni]);
  }
#pragma unroll
  for (int mi = 0; mi < 2; ++mi)
#pragma unroll
    for (int ni = 0; ni < 2; ++ni) {
      const int col = 32 * wc + 16 * ni + ln;
      const int jb = 32 * wr + 16 * mi + 4 * lq;
      U4 o4;
#pragma unroll
      for (int r = 0; r < 4; ++r)
        o4.h[r] = __float2bfloat16(acc[mi][ni][r] + bias2s[col] + betas[jb + r][col & 15]);
      *(uint2*)&obuf[col][jb] = o4.u;
    }
  __syncthreads();
  {
    const int oc = t >> 2, js = (t & 3) * 16;
    bf16* dp = bias_all + (size_t)oc * S * S + (size_t)i * S + j0 + js;
    *(s8v*)dp = *(const s8v*)&obuf[oc][js];
    *(s8v*)(dp + 8) = *(const s8v*)&obuf[oc][js + 8];
  }
}

// ---------------- helpers shared by GEMMs ----------------
DEV s8v combineRT(s8v x, s8v y, int amode) {
  U8 ux, uy, rr;
  ux.s = x; uy.s = y;
#pragma unroll
  for (int j = 0; j < 8; ++j) {
    const float fx = __bfloat162float(ux.h[j]);
    const float fy = __bfloat162float(uy.h[j]);
    const float tt = sigmoidf_(fx);
    rr.h[j] = __float2bfloat16((amode == 2 ? fx * tt : tt) * fy);
  }
  return rr.s;
}

DEV s8v combineFlash(const float* opart, const float* ml, const bf16* gate,
                     int row, int k) {
  const int h = k / DH;
  const float2 m1 = ((const float2*)ml)[(size_t)h * S + row];
  const float2 m2 = ((const float2*)ml)[(size_t)(NHEAD + h) * S + row];
  const float M = fmaxf(m1.x, m2.x);
  const float w1 = __expf(m1.x - M), w2 = __expf(m2.x - M);
  const float inv = 1.0f / (w1 * m1.y + w2 * m2.y);
  const float* o1p = opart + (size_t)row * CA + k;
  const float* o2p = opart + (size_t)S * CA + (size_t)row * CA + k;
  U8 g; g.s = *(const s8v*)(gate + (size_t)row * 3072 + k);
  U8 r;
#pragma unroll
  for (int j = 0; j < 8; ++j) {
    const float v = (w1 * o1p[j] + w2 * o2p[j]) * inv;
    r.h[j] = __float2bfloat16(sigmoidf_(__bfloat162float(g.h[j])) * v);
  }
  return r.s;
}

// ---------------- unified reg-staged GEMM, 64x128 tile, paired via z ----------------
struct GemmAArgs {
  const bf16* A0[2]; int lda0[2];
  const bf16* Bt[2];
  const float* bias[2];
  void* C[2];
  int K[2]; int N[2]; int nb[2];
  int outMode[2];  // 0 bf16, 1 f32+sigmoid
  bf16* vT;   // z0 only: cols [1536,2304) -> vT[n-1536][m]
};

__global__ __launch_bounds__(256) void gemmA(GemmAArgs ga) {
  const int z = blockIdx.z;
  if ((int)blockIdx.x >= ga.nb[z]) return;
  __shared__ s8v As[512];
  __shared__ s8v Bs[1024];
  const bf16* A0 = ga.A0[z]; const int lda0 = ga.lda0[z];
  const bf16* Bt = ga.Bt[z];
  const float* bias = ga.bias[z];
  const int K = ga.K[z], N = ga.N[z], om = ga.outMode[z];
  const int t = threadIdx.x;
  const int lane = t & 63, wid = t >> 6;
  const int wr = wid >> 1, wc = wid & 1;
  const int ln = lane & 15, lq = lane >> 4;
  const int m0 = blockIdx.y * 64, n0 = blockIdx.x * 128;
  int rowA[2], slA[2], swzA[2];
#pragma unroll
  for (int q = 0; q < 2; ++q) {
    const int u = q * 256 + t;
    rowA[q] = u >> 3; slA[q] = u & 7;
    swzA[q] = rowA[q] * 8 + (slA[q] ^ (rowA[q] & 7));
  }
  int rowB[4], slB[4], swzB[4];
#pragma unroll
  for (int q = 0; q < 4; ++q) {
    const int u = q * 256 + t;
    rowB[q] = u >> 3; slB[q] = u & 7;
    swzB[q] = rowB[q] * 8 + (slB[q] ^ (rowB[q] & 7));
  }
  f4v acc[2][4] = {};
  s8v ra[2], rb[4];
#pragma unroll
  for (int q = 0; q < 2; ++q)
    ra[q] = *(const s8v*)(A0 + (size_t)(m0 + rowA[q]) * lda0 + slA[q] * 8);
#pragma unroll
  for (int q = 0; q < 4; ++q)
    rb[q] = *(const s8v*)(Bt + (size_t)(n0 + rowB[q]) * K + slB[q] * 8);
  for (int ks = 0;;) {
    __syncthreads();
#pragma unroll
    for (int q = 0; q < 2; ++q) As[swzA[q]] = ra[q];
#pragma unroll
    for (int q = 0; q < 4; ++q) Bs[swzB[q]] = rb[q];
    const int ksn = ks + 64;
    if (ksn < K) {
#pragma unroll
      for (int q = 0; q < 2; ++q)
        ra[q] = *(const s8v*)(A0 + (size_t)(m0 + rowA[q]) * lda0 + ksn + slA[q] * 8);
#pragma unroll
      for (int q = 0; q < 4; ++q)
        rb[q] = *(const s8v*)(Bt + (size_t)(n0 + rowB[q]) * K + ksn + slB[q] * 8);
    }
    __syncthreads();
#pragma unroll
    for (int kk = 0; kk < 2; ++kk) {
      const int sl = (lq + 4 * kk) ^ (ln & 7);
      s8v a[2], b[4];
#pragma unroll
      for (int mi = 0; mi < 2; ++mi) a[mi] = As[(32 * wr + 16 * mi + ln) * 8 + sl];
#pragma unroll
      for (int ni = 0; ni < 4; ++ni) b[ni] = Bs[(64 * wc + 16 * ni + ln) * 8 + sl];
#pragma unroll
      for (int mi = 0; mi < 2; ++mi)
#pragma unroll
        for (int ni = 0; ni < 4; ++ni) acc[mi][ni] = mfma16(a[mi], b[ni], acc[mi][ni]);
    }
    ks = ksn;
    if (ks >= K) break;
  }
  const bool vdiv = (ga.vT != nullptr) && (z == 0) && (n0 >= 1536) && (n0 < 2304);
#pragma unroll
  for (int ni = 0; ni < 4; ++ni) {
    const int n = n0 + 64 * wc + 16 * ni + ln;
    const float bv = bias ? bias[n] : 0.f;
#pragma unroll
    for (int mi = 0; mi < 2; ++mi) {
      const int mb = m0 + 32 * wr + 16 * mi + 4 * lq;
      if (vdiv) {
        U4 o4;
#pragma unroll
        for (int r = 0; r < 4; ++r) o4.h[r] = __float2bfloat16(acc[mi][ni][r] + bv);
        *(uint2*)(ga.vT + (size_t)(n - 1536) * S + mb) = o4.u;
      } else if (om == 0) {
        bf16* Cb = (bf16*)ga.C[z];
#pragma unroll
        for (int r = 0; r < 4; ++r)
          Cb[(size_t)(mb + r) * N + n] = __float2bfloat16(acc[mi][ni][r] + bv);
      } else {
        float* Cf = (float*)ga.C[z];
#pragma unroll
        for (int r = 0; r < 4; ++r)
          Cf[(size_t)(mb + r) * N + n] = sigmoidf_(acc[mi][ni][r] + bv);
      }
    }
  }
}

// ---------------- tail: (combineFlash@wo) & (swiglu@wout), gated sum -> a_next f32 ----
struct GemmTailArgs {
  const float* opA; const float* mlA; const bf16* gateA;
  const bf16* swg;
  const bf16* BtWo; const bf16* BtWout;
  const float* sg;   // +b*1536, ld 6144
  float* out;        // a_next f32 (ld 768)
};

__global__ __launch_bounds__(256) void gemm_tail(GemmTailArgs ga) {
  __shared__ s8v As[512];   // 64 x 64 bf16
  __shared__ s8v Bs[512];
  const int t = threadIdx.x;
  const int lane = t & 63, wid = t >> 6;
  const int wr = wid >> 1, wc = wid & 1;
  const int ln = lane & 15, lq = lane >> 4;
  const int m0 = blockIdx.y * 64, n0 = blockIdx.x * 64;
  int rowS[2], slS[2], swz[2];
#pragma unroll
  for (int q = 0; q < 2; ++q) {
    const int u = q * 256 + t;
    rowS[q] = u >> 3; slS[q] = u & 7;
    swz[q] = rowS[q] * 8 + (slS[q] ^ (rowS[q] & 7));
  }
  f4v acc1[2][2] = {}, acc2[2][2] = {};
  // phase 1: K=768, A = combineFlash, B = WT_wo
  for (int ks = 0; ks < 768; ks += 64) {
    __syncthreads();
#pragma unroll
    for (int q = 0; q < 2; ++q) {
      As[swz[q]] = combineFlash(ga.opA, ga.mlA, ga.gateA, m0 + rowS[q], ks + slS[q] * 8);
      Bs[swz[q]] = *(const s8v*)(ga.BtWo + (size_t)(n0 + rowS[q]) * 768 + ks + slS[q] * 8);
    }
    __syncthreads();
#pragma unroll
    for (int kk = 0; kk < 2; ++kk) {
      const int sl = (lq + 4 * kk) ^ (ln & 7);
      s8v a[2], b[2];
#pragma unroll
      for (int mi = 0; mi < 2; ++mi) a[mi] = As[(32 * wr + 16 * mi + ln) * 8 + sl];
#pragma unroll
      for (int ni = 0; ni < 2; ++ni) b[ni] = Bs[(32 * wc + 16 * ni + ln) * 8 + sl];
#pragma unroll
      for (int mi = 0; mi < 2; ++mi)
#pragma unroll
        for (int ni = 0; ni < 2; ++ni) acc1[mi][ni] = mfma16(a[mi], b[ni], acc1[mi][ni]);
    }
  }
  // phase 2: K=1536, A = swiglu(swg), B = WT_wout
  for (int ks = 0; ks < 1536; ks += 64) {
    __syncthreads();
#pragma unroll
    for (int q = 0; q < 2; ++q) {
      const s8v x = *(const s8v*)(ga.swg + (size_t)(m0 + rowS[q]) * 3072 + ks + slS[q] * 8);
      const s8v y = *(const s8v*)(ga.swg + (size_t)(m0 + rowS[q]) * 3072 + 1536 + ks + slS[q] * 8);
      As[swz[q]] = combineRT(x, y, 2);
      Bs[swz[q]] = *(const s8v*)(ga.BtWout + (size_t)(n0 + rowS[q]) * 1536 + ks + slS[q] * 8);
    }
    __syncthreads();
#pragma unroll
    for (int kk = 0; kk < 2; ++kk) {
      const int sl = (lq + 4 * kk) ^ (ln & 7);
      s8v a[2], b[2];
#pragma unroll
      for (int mi = 0; mi < 2; ++mi) a[mi] = As[(32 * wr + 16 * mi + ln) * 8 + sl];
#pragma unroll
      for (int ni = 0; ni < 2; ++ni) b[ni] = Bs[(32 * wc + 16 * ni + ln) * 8 + sl];
#pragma unroll
      for (int mi = 0; mi < 2; ++mi)
#pragma unroll
        for (int ni = 0; ni < 2; ++ni) acc2[mi][ni] = mfma16(a[mi], b[ni], acc2[mi][ni]);
    }
  }
  // epilogue: out = sgA*acc1 + sgT*acc2 (f32)
#pragma unroll
  for (int ni = 0; ni < 2; ++ni) {
    const int n = n0 + 32 * wc + 16 * ni + ln;
#pragma unroll
    for (int mi = 0; mi < 2; ++mi) {
      const int mb = m0 + 32 * wr + 16 * mi + 4 * lq;
#pragma unroll
      for (int r = 0; r < 4; ++r) {
        const int row = mb + r;
        const float sgA = ga.sg[(size_t)row * 6144 + n];
        const float sgT = ga.sg[(size_t)row * 6144 + 768 + n];
        ga.out[(size_t)row * CA + n] = sgA * acc1[mi][ni][r] + sgT * acc2[mi][ni][r];
      }
    }
  }
}

// ---------------- flash attention, j-split x2 + setprio ----------------
__global__ __launch_bounds__(256) void flash_split(const bf16* __restrict__ qkvg,
                                                   const bf16* __restrict__ vT,
                                                   const bf16* __restrict__ bias_all,
                                                   float* __restrict__ opart,
                                                   float* __restrict__ ml, int blk) {
  __shared__ s8v Qs[64 * 8];
  __shared__ s8v Ks[2][64 * 8];
  __shared__ s8v Vs[2][48 * 8];
  __shared__ s8v Bs[2][64 * 8];
  __shared__ bf16 PwB[4 * 1024];
  __shared__ float facL[4][16];
  const int t = threadIdx.x;
  const int lane = t & 63, w = t >> 6;
  const int ln = lane & 15, lq = lane >> 4;
  const int h = blockIdx.y, i0 = blockIdx.x * 64, half = blockIdx.z;
  const bf16* bp = bias_all + (size_t)(blk * NHEAD + h) * S * S;
  const float scale = 0.14433756729740643f;

#pragma unroll
  for (int uu = 0; uu < 2; ++uu) {
    const int u = t + 256 * uu, row = u >> 3, sl = u & 7;
    s8v qv{};
    if (sl < 6) qv = *(const s8v*)(qkvg + (size_t)(i0 + row) * 3072 + h * DH + sl * 8);
    Qs[row * 8 + (sl ^ (row & 7))] = qv;
  }

  s8v kr[2], br[2], vr0{}, vr1{};
  auto prefetch = [&](int jt) {
    const int j0 = jt * 64;
#pragma unroll
    for (int uu = 0; uu < 2; ++uu) {
      const int u = t + 256 * uu, row = u >> 3, sl = u & 7;
      s8v kv{};
      if (sl < 6) kv = *(const s8v*)(qkvg + (size_t)(j0 + row) * 3072 + 768 + h * DH + sl * 8);
      kr[uu] = kv;
      br[uu] = *(const s8v*)(bp + (size_t)(i0 + row) * S + j0 + sl * 8);
    }
    { const int d = t >> 3, sl = t & 7;
      vr0 = *(const s8v*)(vT + (size_t)(h * DH + d) * S + j0 + sl * 8); }
    if (t < 128) {
      const int u = 256 + t, d = u >> 3, sl = u & 7;
      vr1 = *(const s8v*)(vT + (size_t)(h * DH + d) * S + j0 + sl * 8);
    }
  };
  auto store_tiles = [&](int pb) {
#pragma unroll
    for (int uu = 0; uu < 2; ++uu) {
      const int u = t + 256 * uu, row = u >> 3, sl = u & 7;
      const int ph = row * 8 + (sl ^ (row & 7));
      Ks[pb][ph] = kr[uu];
      Bs[pb][ph] = br[uu];
    }
    { const int d = t >> 3, sl = t & 7;
      Vs[pb][d * 8 + (sl ^ (d & 7))] = vr0; }
    if (t < 128) {
      const int u = 256 + t, d = u >> 3, sl = u & 7;
      Vs[pb][d * 8 + (sl ^ (d & 7))] = vr1;
    }
  };

  float m_run = -3e30f, l_run = 0.f;
  f4v acc_o[3] = {};
  bf16* pw = PwB + w * 1024;

  prefetch(half * 8);
  for (int jt2 = 0; jt2 < 8; ++jt2) {
    const int pb = jt2 & 1;
    __syncthreads();
    store_tiles(pb);
    __syncthreads();
    if (jt2 < 7) prefetch(half * 8 + jt2 + 1);
    float p[4][4];
    float tmax = -3e30f;
    __builtin_amdgcn_s_setprio(1);
#pragma unroll
    for (int ja = 0; ja < 4; ++ja) {
      f4v accs = {};
#pragma unroll
      for (int ks2 = 0; ks2 < 2; ++ks2) {
        const int sl = (lq + 4 * ks2) ^ (ln & 7);
        const s8v a = Ks[pb][(16 * ja + ln) * 8 + sl];
        const s8v b = Qs[(16 * w + ln) * 8 + sl];
        accs = mfma16(a, b, accs);
      }
      const int jq = 4 * ja + lq;
      const int pu = jq >> 1;
      U4 bv;
      bv.u = *(const uint2*)((const bf16*)(&Bs[pb][0]) +
                             (((16 * w + ln) * 8 + (pu ^ (ln & 7))) * 8 + (jq & 1) * 4));
#pragma unroll
      for (int r = 0; r < 4; ++r) {
        p[ja][r] = accs[r] * scale + __bfloat162float(bv.h[r]);
        tmax = fmaxf(tmax, p[ja][r]);
      }
    }
    __builtin_amdgcn_s_setprio(0);
    tmax = fmaxf(tmax, __shfl_xor(tmax, 16));
    tmax = fmaxf(tmax, __shfl_xor(tmax, 32));
    const float m_new = fmaxf(m_run, tmax);
    const float fac = __expf(m_run - m_new);
    m_run = m_new;
    float psum = 0.f;
#pragma unroll
    for (int ja = 0; ja < 4; ++ja)
#pragma unroll
      for (int r = 0; r < 4; ++r) {
        p[ja][r] = __expf(p[ja][r] - m_new);
        psum += p[ja][r];
      }
    psum += __shfl_xor(psum, 16);
    psum += __shfl_xor(psum, 32);
    l_run = l_run * fac + psum;
    if (lq == 0) facL[w][ln] = fac;
#pragma unroll
    for (int ja = 0; ja < 4; ++ja) {
      const int ju = 4 * ja + lq;
      const int ph = ju ^ ((ln & 7) << 1);
      U4 pk;
#pragma unroll
      for (int r = 0; r < 4; ++r) pk.h[r] = __float2bfloat16(p[ja][r]);
      *(uint2*)(pw + ln * 64 + ph * 4) = pk.u;
    }
    asm volatile("s_waitcnt lgkmcnt(0)" ::: "memory");
    __builtin_amdgcn_sched_barrier(0);
    const float4 fv = *(const float4*)&facL[w][4 * lq];
#pragma unroll
    for (int ni = 0; ni < 3; ++ni) {
      acc_o[ni][0] *= fv.x; acc_o[ni][1] *= fv.y;
      acc_o[ni][2] *= fv.z; acc_o[ni][3] *= fv.w;
    }
    __builtin_amdgcn_s_setprio(1);
#pragma unroll
    for (int ks2 = 0; ks2 < 2; ++ks2) {
      const int pu0 = (2 * lq + 8 * ks2) ^ ((ln & 7) << 1);
      const s8v pa = *(const s8v*)(pw + ln * 64 + pu0 * 4);
      const int slv = (lq + 4 * ks2) ^ (ln & 7);
#pragma unroll
      for (int ni = 0; ni < 3; ++ni) {
        const s8v vb = Vs[pb][(16 * ni + ln) * 8 + slv];
        acc_o[ni] = mfma16(pa, vb, acc_o[ni]);
      }
    }
    __builtin_amdgcn_s_setprio(0);
  }
  if (lq == 0) {
    ((float2*)ml)[(size_t)(half * NHEAD + h) * S + i0 + 16 * w + ln] =
        make_float2(m_run, l_run);
  }
  float* op = opart + (size_t)half * S * CA;
#pragma unroll
  for (int ni = 0; ni < 3; ++ni)
#pragma unroll
    for (int r = 0; r < 4; ++r) {
      const int m = i0 + 16 * w + 4 * lq + r;
      op[(size_t)m * CA + h * DH + 16 * ni + ln] = acc_o[ni][r];
    }
}

__global__ void fill_kernel(float* p, int n, float v) {
  const int i = blockIdx.x * 256 + threadIdx.x;
  if (i < n) p[i] = v;
}

extern "C" void kernel_launch(void* const* d_in, const int* in_sizes, int n_in,
                              void* d_out, int out_size, void* d_ws, size_t ws_size,
                              hipStream_t stream) {
  (void)in_sizes; (void)n_in;
  const float* a_in = (const float*)d_in[0];
  const float* s_in = (const float*)d_in[1];
  const float* z_in = (const float*)d_in[2];
  const float* beta = (const float*)d_in[3];
  const float* ln_s_w_attn = (const float*)d_in[4];
  const float* wg_attn = (const float*)d_in[5];
  const float* wb_attn = (const float*)d_in[6];
  const float* wq = (const float*)d_in[7];
  const float* bq = (const float*)d_in[8];
  const float* wk = (const float*)d_in[9];
  const float* wv = (const float*)d_in[10];
  const float* ln_z_w = (const float*)d_in[11];
  const float* ln_z_b = (const float*)d_in[12];
  const float* wpb = (const float*)d_in[13];
  const float* wgate = (const float*)d_in[14];
  const float* wo = (const float*)d_in[15];
  const float* wsg_attn = (const float*)d_in[16];
  const float* bsg_attn = (const float*)d_in[17];
  const float* ln_s_w_tr = (const float*)d_in[18];
  const float* wg_tr = (const float*)d_in[19];
  const float* wb_tr = (const float*)d_in[20];
  const float* w_swish = (const float*)d_in[21];
  const float* w_gate2 = (const float*)d_in[22];
  const float* wsg_tr = (const float*)d_in[23];
  const float* bsg_tr = (const float*)d_in[24];
  const float* w_out = (const float*)d_in[25];

  char* wp = (char*)d_ws;
  size_t used = 0;
  auto alloc = [&](size_t bytes) -> void* {
    void* p = wp + used;
    used += (bytes + 255) & ~(size_t)255;
    return p;
  };
  bf16* bias_all = (bf16*)alloc((size_t)64 * S * S * 2);
  bf16* WT_ada = (bf16*)alloc((size_t)4 * 3072 * 384 * 2);
  bf16* WT_sg = (bf16*)alloc((size_t)4 * 1536 * 384 * 2);
  bf16* WT_qkvg = (bf16*)alloc((size_t)4 * 3072 * 768 * 2);
  bf16* WT_wo = (bf16*)alloc((size_t)4 * 768 * 768 * 2);
  bf16* WT_mlp = (bf16*)alloc((size_t)4 * 3072 * 768 * 2);
  bf16* WT_wout = (bf16*)alloc((size_t)4 * 768 * 1536 * 2);
  float* biasQKVG = (float*)alloc(4 * 3072 * 4);
  float* biasSG = (float*)alloc(6144 * 4);
  bf16* W2T = (bf16*)alloc(64 * 128 * 2);
  float* bias2 = (float*)alloc(64 * 4);
  bf16* ada_all = (bf16*)alloc((size_t)S * 12288 * 2);
  float* sg_all = (float*)alloc((size_t)S * 6144 * 4);
  bf16* s_hat = (bf16*)alloc((size_t)S * CS * 2);
  bf16* s_bf = (bf16*)alloc((size_t)S * CS * 2);
  float* a_buf = (float*)alloc((size_t)S * CA * 4);
  bf16* ah_attn = (bf16*)alloc((size_t)S * CA * 2);
  bf16* ah_tr = (bf16*)alloc((size_t)S * CA * 2);
  bf16* qkvg = (bf16*)alloc((size_t)S * 3072 * 2);
  bf16* vT = (bf16*)alloc((size_t)CA * S * 2);
  bf16* swg = (bf16*)alloc((size_t)S * 3072 * 2);
  float* opart = (float*)alloc((size_t)2 * S * CA * 4);
  float* ml = (float*)alloc((size_t)2 * NHEAD * S * 8);
  if (used > ws_size) {
    fill_kernel<<<(out_size + 255) / 256, 256, 0, stream>>>((float*)d_out, out_size, 12345.0f);
    return;
  }

  const dim3 B256(256);

  {  // launch 1: all prep (transposes + biases + s-LN)
    PrepFatArgs pa{};
    pa.tsrc[0] = wg_attn;  pa.tdst[0] = WT_ada + (size_t)0 * 384;    pa.tcs[0] = ln_s_w_attn; pa.tdstZ[0] = 3072 * 384;
    pa.tsrc[1] = wb_attn;  pa.tdst[1] = WT_ada + (size_t)768 * 384;  pa.tcs[1] = ln_s_w_attn; pa.tdstZ[1] = 3072 * 384;
    pa.tsrc[2] = wg_tr;    pa.tdst[2] = WT_ada + (size_t)1536 * 384; pa.tcs[2] = ln_s_w_tr;   pa.tdstZ[2] = 3072 * 384;
    pa.tsrc[3] = wb_tr;    pa.tdst[3] = WT_ada + (size_t)2304 * 384; pa.tcs[3] = ln_s_w_tr;   pa.tdstZ[3] = 3072 * 384;
    pa.tsrc[4] = wsg_attn; pa.tdst[4] = WT_sg + (size_t)0 * 384;     pa.tcs[4] = nullptr;     pa.tdstZ[4] = 1536 * 384;
    pa.tsrc[5] = wsg_tr;   pa.tdst[5] = WT_sg + (size_t)768 * 384;   pa.tcs[5] = nullptr;     pa.tdstZ[5] = 1536 * 384;
    pa.tsrc[6] = wq;    pa.tdst[6] = WT_qkvg + (size_t)0 * 768;    pa.tdstZ[6] = 3072 * 768;
    pa.tsrc[7] = wk;    pa.tdst[7] = WT_qkvg + (size_t)768 * 768;  pa.tdstZ[7] = 3072 * 768;
    pa.tsrc[8] = wv;    pa.tdst[8] = WT_qkvg + (size_t)1536 * 768; pa.tdstZ[8] = 3072 * 768;
    pa.tsrc[9] = wgate; pa.tdst[9] = WT_qkvg + (size_t)2304 * 768; pa.tdstZ[9] = 3072 * 768;
    pa.tsrc[10] = wo;   pa.tdst[10] = WT_wo;                       pa.tdstZ[10] = 768 * 768;
    pa.tsrc[11] = w_swish; pa.tdst[11] = WT_mlp + (size_t)0 * 768;    pa.tdstZ[11] = 3072 * 768;
    pa.tsrc[12] = w_gate2; pa.tdst[12] = WT_mlp + (size_t)1536 * 768; pa.tdstZ[12] = 3072 * 768;
    pa.tsrc[13] = w_out; pa.tdst[13] = WT_wout; pa.tdstZ[13] = 768 * 1536;
    pa.ln_z_w = ln_z_w; pa.ln_z_b = ln_z_b; pa.wpb = wpb;
    pa.bq = bq; pa.bsg_a = bsg_attn; pa.bsg_t = bsg_tr;
    pa.W2T = W2T; pa.bias2 = bias2; pa.biasQKVG = biasQKVG; pa.biasSG = biasSG;
    pa.s_in = s_in; pa.s_hat = s_hat; pa.s_bf = s_bf;
    prep_fat<<<33329, B256, 0, stream>>>(pa);
  }

  zbias_kernel<<<dim3(16, 1024), B256, 0, stream>>>(z_in, beta, W2T, bias2, bias_all);

  {  // hoisted: z0 ada (N=12288), z1 sg (N=6144, f32+sigmoid)
    GemmAArgs ga{};
    ga.A0[0] = s_hat; ga.lda0[0] = 384; ga.Bt[0] = WT_ada; ga.bias[0] = nullptr;
    ga.C[0] = ada_all; ga.K[0] = 384; ga.N[0] = 12288; ga.nb[0] = 96; ga.outMode[0] = 0;
    ga.A0[1] = s_bf; ga.lda0[1] = 384; ga.Bt[1] = WT_sg; ga.bias[1] = biasSG;
    ga.C[1] = sg_all; ga.K[1] = 384; ga.N[1] = 6144; ga.nb[1] = 48; ga.outMode[1] = 1;
    ga.vT = nullptr;
    gemmA<<<dim3(96, 16, 2), B256, 0, stream>>>(ga);
  }

  ln_adaln2<<<S, B256, 0, stream>>>(a_in, ada_all, ah_attn, ah_tr);
  for (int b = 0; b < NBLK; ++b) {
    {  // z0 qkvg (with vT divert), z1 mlp(swg)
      GemmAArgs ga{};
      ga.A0[0] = ah_attn; ga.lda0[0] = 768; ga.Bt[0] = WT_qkvg + (size_t)b * 3072 * 768;
      ga.bias[0] = biasQKVG + b * 3072; ga.C[0] = qkvg; ga.K[0] = 768; ga.N[0] = 3072;
      ga.nb[0] = 24; ga.outMode[0] = 0;
      ga.A0[1] = ah_tr; ga.lda0[1] = 768; ga.Bt[1] = WT_mlp + (size_t)b * 3072 * 768;
      ga.bias[1] = nullptr; ga.C[1] = swg; ga.K[1] = 768; ga.N[1] = 3072;
      ga.nb[1] = 24; ga.outMode[1] = 0;
      ga.vT = vT;
      gemmA<<<dim3(24, 16, 2), B256, 0, stream>>>(ga);
    }
    flash_split<<<dim3(16, 16, 2), B256, 0, stream>>>(qkvg, vT, bias_all, opart, ml, b);
    float* a_next = (b == NBLK - 1) ? (float*)d_out : a_buf;
    {  // fused tail: gated wo+wout GEMMs -> a_next (f32)
      GemmTailArgs ta{};
      ta.opA = opart; ta.mlA = ml; ta.gateA = qkvg + 2304;
      ta.swg = swg;
      ta.BtWo = WT_wo + (size_t)b * 768 * 768;
      ta.BtWout = WT_wout + (size_t)b * 768 * 1536;
      ta.sg = sg_all + (size_t)b * 1536;
      ta.out = a_next;
      gemm_tail<<<dim3(12, 16), B256, 0, stream>>>(ta);
    }
    if (b < NBLK - 1)
      ln_adaln2<<<S, B256, 0, stream>>>(a_next, ada_all + (size_t)(b + 1) * 3072, ah_attn, ah_tr);
  }
}

// Round 13
// 542.213 us; speedup vs baseline: 1.4565x; 1.4565x over previous
//
#include <hip/hip_runtime.h>
#include <hip/hip_bf16.h>

typedef __hip_bfloat16 bf16;
typedef __attribute__((ext_vector_type(8))) short s8v;   // 8 bf16 = 16B
typedef __attribute__((ext_vector_type(4))) float f4v;

constexpr int S = 1024, CA = 768, CS = 384, CZ = 128, NHID = 1536;
constexpr int NBLK = 4, NHEAD = 16, DH = 48;
constexpr float EPS = 1e-5f;

#define DEV static __device__ __forceinline__

DEV float sigmoidf_(float x) { return 1.0f / (1.0f + __expf(-x)); }

DEV f4v mfma16(s8v a, s8v b, f4v c) {
  return __builtin_amdgcn_mfma_f32_16x16x32_bf16(a, b, c, 0, 0, 0);
}

union U8 { s8v s; bf16 h[8]; };
union U4 { uint2 u; bf16 h[4]; };

DEV float wred_sum(float v) {
#pragma unroll
  for (int o = 32; o; o >>= 1) v += __shfl_xor(v, o);
  return v;
}

// ================= prep_fat: transposes + bias prep + s-LN, one launch =================
struct PrepFatArgs {
  const float* tsrc[14];
  bf16* tdst[14];
  const float* tcs[14];
  long tdstZ[14];
  const float *ln_z_w, *ln_z_b, *wpb, *bq, *bsg_a, *bsg_t;
  bf16* W2T; float* bias2; float* biasQKVG; float* biasSG;
  const float* s_in; bf16* s_hat; bf16* s_bf;
};

__global__ __launch_bounds__(256) void prep_fat(PrepFatArgs a) {
  __shared__ __align__(16) float tile[1056];
  const int bid = blockIdx.x, t = threadIdx.x;
  if (bid < 32256) {  // transposes
    int ti, blk, x, y, K, N;
    if (bid < 6912) {
      const int lb = bid; ti = lb / 1152; const int r2 = lb % 1152;
      blk = r2 / 288; const int rem = r2 % 288; x = rem % 24; y = rem / 24; K = 384; N = 768;
    } else if (bid < 18432) {
      const int lb = bid - 6912; ti = 6 + lb / 2304; const int r2 = lb % 2304;
      blk = r2 / 576; const int rem = r2 % 576; x = rem % 24; y = rem / 24; K = 768; N = 768;
    } else if (bid < 27648) {
      const int lb = bid - 18432; ti = 11 + lb / 4608; const int r2 = lb % 4608;
      blk = r2 / 1152; const int rem = r2 % 1152; x = rem % 48; y = rem / 48; K = 768; N = 1536;
    } else {
      const int lb = bid - 27648; ti = 13; blk = lb / 1152;
      const int rem = lb % 1152; x = rem % 24; y = rem / 24; K = 1536; N = 768;
    }
    const float* src = a.tsrc[ti] + (size_t)blk * K * N;
    bf16* dst = a.tdst[ti] + (size_t)blk * a.tdstZ[ti];
    const float* cs = a.tcs[ti] ? (a.tcs[ti] + blk * CS) : nullptr;
    const int k0 = y * 32, n0 = x * 32, tx = t & 31, ty = t >> 5;
#pragma unroll
    for (int q = 0; q < 4; ++q) {
      const int k = k0 + ty + 8 * q;
      float v = src[(size_t)k * N + n0 + tx];
      if (cs) v *= cs[k];
      tile[(ty + 8 * q) * 33 + tx] = v;
    }
    __syncthreads();
#pragma unroll
    for (int q = 0; q < 4; ++q)
      dst[(size_t)(n0 + ty + 8 * q) * K + k0 + tx] = __float2bfloat16(tile[tx * 33 + ty + 8 * q]);
    return;
  }
  if (bid < 32305) {  // bias prep
    const int pid = bid - 32256;
    if (pid == 48) {
      for (int f = t; f < 64 * CZ; f += 256) {
        const int col = f >> 7, c = f & 127, b = col >> 4, h = col & 15;
        a.W2T[f] = __float2bfloat16(a.ln_z_w[b * CZ + c] * a.wpb[(b * CZ + c) * NHEAD + h]);
      }
      if (t < 64) {
        const int b = t >> 4, h = t & 15;
        float sum = 0.f;
        for (int c = 0; c < CZ; ++c)
          sum += a.ln_z_b[b * CZ + c] * a.wpb[(b * CZ + c) * NHEAD + h];
        a.bias2[t] = sum;
      }
      return;
    }
    const int g = pid * 256 + t;
    if (g < 4 * 3072) {
      const int b = g / 3072, c = g % 3072;
      a.biasQKVG[g] = (c < 768) ? a.bq[b * 768 + c] : 0.f;
    }
    if (g < 6144) {
      const int b = g / 1536, c = g % 1536;
      a.biasSG[g] = (c < 768) ? a.bsg_a[b * 768 + c] : a.bsg_t[b * 768 + c - 768];
    }
    return;
  }
  {  // rowln_s
    float* red = tile;
    const size_t row = bid - 32305;
    float4 v = make_float4(0.f, 0.f, 0.f, 0.f);
    if (t < CS / 4) v = ((const float4*)(a.s_in + row * CS))[t];
    float sum = v.x + v.y + v.z + v.w;
    float sq = v.x * v.x + v.y * v.y + v.z * v.z + v.w * v.w;
    sum = wred_sum(sum); sq = wred_sum(sq);
    const int wv = t >> 6;
    if ((t & 63) == 0) { red[2 * wv] = sum; red[2 * wv + 1] = sq; }
    __syncthreads();
    sum = red[0] + red[2] + red[4] + red[6];
    sq = red[1] + red[3] + red[5] + red[7];
    const float m = sum / CS;
    const float rstd = rsqrtf(sq / CS - m * m + EPS);
    if (t < CS / 4) {
      U4 oh, ob_;
      oh.h[0] = __float2bfloat16((v.x - m) * rstd); oh.h[1] = __float2bfloat16((v.y - m) * rstd);
      oh.h[2] = __float2bfloat16((v.z - m) * rstd); oh.h[3] = __float2bfloat16((v.w - m) * rstd);
      ob_.h[0] = __float2bfloat16(v.x); ob_.h[1] = __float2bfloat16(v.y);
      ob_.h[2] = __float2bfloat16(v.z); ob_.h[3] = __float2bfloat16(v.w);
      *(uint2*)(a.s_hat + row * CS + 4 * t) = oh.u;
      *(uint2*)(a.s_bf + row * CS + 4 * t) = ob_.u;
    }
  }
}

// ---------------- fused LN(a) + both adaLNs (block 0 entry) ----------------
__global__ __launch_bounds__(256) void ln_adaln2(const float* __restrict__ a,
                                                 const bf16* __restrict__ ada,
                                                 bf16* __restrict__ ah_attn,
                                                 bf16* __restrict__ ah_tr) {
  __shared__ float red[8];
  const int t = threadIdx.x;
  const size_t row = blockIdx.x;
  float4 v = make_float4(0.f, 0.f, 0.f, 0.f);
  if (t < 192) v = ((const float4*)(a + row * CA))[t];
  float sum = v.x + v.y + v.z + v.w;
  float sq = v.x * v.x + v.y * v.y + v.z * v.z + v.w * v.w;
  sum = wred_sum(sum); sq = wred_sum(sq);
  const int wv = t >> 6;
  if ((t & 63) == 0) { red[2 * wv] = sum; red[2 * wv + 1] = sq; }
  __syncthreads();
  sum = red[0] + red[2] + red[4] + red[6];
  sq = red[1] + red[3] + red[5] + red[7];
  const float m = sum / CA;
  const float rstd = rsqrtf(sq / CA - m * m + EPS);
  if (t < 192) {
    const float an[4] = {(v.x - m) * rstd, (v.y - m) * rstd, (v.z - m) * rstd, (v.w - m) * rstd};
    const bf16* ar = ada + row * 12288 + 4 * t;
    U4 g1, b1, g2, b2, o1, o2;
    g1.u = *(const uint2*)(ar);
    b1.u = *(const uint2*)(ar + 768);
    g2.u = *(const uint2*)(ar + 1536);
    b2.u = *(const uint2*)(ar + 2304);
#pragma unroll
    for (int j = 0; j < 4; ++j) {
      o1.h[j] = __float2bfloat16(sigmoidf_(__bfloat162float(g1.h[j])) * an[j] + __bfloat162float(b1.h[j]));
      o2.h[j] = __float2bfloat16(sigmoidf_(__bfloat162float(g2.h[j])) * an[j] + __bfloat162float(b2.h[j]));
    }
    *(uint2*)(ah_attn + row * CA + 4 * t) = o1.u;
    *(uint2*)(ah_tr + row * CA + 4 * t) = o2.u;
  }
}

// ---------------- fused: a=sgA*att+sgT*tr ; LN(a) ; adaLN for NEXT block ----------------
__global__ __launch_bounds__(256) void final_adaln(const float* __restrict__ sg,
                                                   const bf16* __restrict__ att,
                                                   const bf16* __restrict__ tr,
                                                   const bf16* __restrict__ ada,
                                                   bf16* __restrict__ ah_attn,
                                                   bf16* __restrict__ ah_tr) {
  __shared__ float red[8];
  const int t = threadIdx.x;
  const size_t row = blockIdx.x;
  float o[4] = {0.f, 0.f, 0.f, 0.f};
  if (t < 192) {
    const float4 sa = *(const float4*)(sg + row * 6144 + 4 * t);
    const float4 st = *(const float4*)(sg + row * 6144 + 768 + 4 * t);
    U4 av, tv;
    av.u = *(const uint2*)(att + row * CA + 4 * t);
    tv.u = *(const uint2*)(tr + row * CA + 4 * t);
    o[0] = sa.x * __bfloat162float(av.h[0]) + st.x * __bfloat162float(tv.h[0]);
    o[1] = sa.y * __bfloat162float(av.h[1]) + st.y * __bfloat162float(tv.h[1]);
    o[2] = sa.z * __bfloat162float(av.h[2]) + st.z * __bfloat162float(tv.h[2]);
    o[3] = sa.w * __bfloat162float(av.h[3]) + st.w * __bfloat162float(tv.h[3]);
  }
  float sum = o[0] + o[1] + o[2] + o[3];
  float sq = o[0] * o[0] + o[1] * o[1] + o[2] * o[2] + o[3] * o[3];
  sum = wred_sum(sum); sq = wred_sum(sq);
  const int wv = t >> 6;
  if ((t & 63) == 0) { red[2 * wv] = sum; red[2 * wv + 1] = sq; }
  __syncthreads();
  sum = red[0] + red[2] + red[4] + red[6];
  sq = red[1] + red[3] + red[5] + red[7];
  const float m = sum / CA;
  const float rstd = rsqrtf(sq / CA - m * m + EPS);
  if (t < 192) {
    const bf16* ar = ada + row * 12288 + 4 * t;
    U4 g1, b1, g2, b2, o1, o2;
    g1.u = *(const uint2*)(ar);
    b1.u = *(const uint2*)(ar + 768);
    g2.u = *(const uint2*)(ar + 1536);
    b2.u = *(const uint2*)(ar + 2304);
#pragma unroll
    for (int j = 0; j < 4; ++j) {
      const float an = (o[j] - m) * rstd;
      o1.h[j] = __float2bfloat16(sigmoidf_(__bfloat162float(g1.h[j])) * an + __bfloat162float(b1.h[j]));
      o2.h[j] = __float2bfloat16(sigmoidf_(__bfloat162float(g2.h[j])) * an + __bfloat162float(b2.h[j]));
    }
    *(uint2*)(ah_attn + row * CA + 4 * t) = o1.u;
    *(uint2*)(ah_tr + row * CA + 4 * t) = o2.u;
  }
}

// ---------------- last block: out = sgA*att + sgT*tr (f32) ----------------
__global__ __launch_bounds__(256) void ew_final(const float* __restrict__ sg,
                                                const bf16* __restrict__ att,
                                                const bf16* __restrict__ tr,
                                                float* __restrict__ out) {
  const int i = blockIdx.x * 256 + threadIdx.x;
  const int row = i / 192, col = (i % 192) * 4;
  const float4 sa = *(const float4*)(sg + (size_t)row * 6144 + col);
  const float4 st = *(const float4*)(sg + (size_t)row * 6144 + 768 + col);
  U4 av, tv;
  av.u = *(const uint2*)(att + (size_t)row * CA + col);
  tv.u = *(const uint2*)(tr + (size_t)row * CA + col);
  float4 o;
  o.x = sa.x * __bfloat162float(av.h[0]) + st.x * __bfloat162float(tv.h[0]);
  o.y = sa.y * __bfloat162float(av.h[1]) + st.y * __bfloat162float(tv.h[1]);
  o.z = sa.z * __bfloat162float(av.h[2]) + st.z * __bfloat162float(tv.h[2]);
  o.w = sa.w * __bfloat162float(av.h[3]) + st.w * __bfloat162float(tv.h[3]);
  *(float4*)(out + (size_t)row * CA + col) = o;
}

// ---------------- zbias: LN(z)@W2T + bias2 + beta -> bf16 [64][S][S], MFMA ----------------
__global__ __launch_bounds__(256) void zbias_kernel(const float* __restrict__ z,
                                                    const float* __restrict__ beta,
                                                    const bf16* __restrict__ W2T,
                                                    const float* __restrict__ bias2,
                                                    bf16* __restrict__ bias_all) {
  __shared__ s8v zt8[64 * 16];
  __shared__ s8v w2s[64 * 16];
  __shared__ float betas[64][17];
  __shared__ float bias2s[64];
  __shared__ bf16 obuf[64][72];
  const int t = threadIdx.x;
  const int i = blockIdx.y, j0 = blockIdx.x * 64;
#pragma unroll
  for (int q = 0; q < 4; ++q) {
    const int u = q * 256 + t;
    const int row = u >> 4, sl = u & 15;
    w2s[row * 16 + (sl ^ (row & 7))] = *(const s8v*)(W2T + row * CZ + sl * 8);
  }
  if (t < 64) bias2s[t] = bias2[t];
  {
    const int j = t >> 2, h4 = t & 3;
    const float4 bv = *(const float4*)(beta + ((size_t)i * S + j0 + j) * NHEAD + 4 * h4);
    betas[j][4 * h4 + 0] = bv.x; betas[j][4 * h4 + 1] = bv.y;
    betas[j][4 * h4 + 2] = bv.z; betas[j][4 * h4 + 3] = bv.w;
  }
  {
    const int p = t >> 2, q = t & 3;
    const float* zr = z + ((size_t)i * S + j0 + p) * CZ + q * 32;
    float vals[32];
    float sum = 0.f, sq = 0.f;
#pragma unroll
    for (int k4 = 0; k4 < 8; ++k4) {
      const float4 xv = *(const float4*)(zr + 4 * k4);
      vals[4 * k4 + 0] = xv.x; vals[4 * k4 + 1] = xv.y;
      vals[4 * k4 + 2] = xv.z; vals[4 * k4 + 3] = xv.w;
      sum += xv.x + xv.y + xv.z + xv.w;
      sq += xv.x * xv.x + xv.y * xv.y + xv.z * xv.z + xv.w * xv.w;
    }
    sum += __shfl_xor(sum, 1); sum += __shfl_xor(sum, 2);
    sq += __shfl_xor(sq, 1); sq += __shfl_xor(sq, 2);
    const float m = sum / CZ;
    const float rstd = rsqrtf(sq / CZ - m * m + EPS);
#pragma unroll
    for (int u = 0; u < 4; ++u) {
      U8 pk;
#pragma unroll
      for (int e = 0; e < 8; ++e) pk.h[e] = __float2bfloat16((vals[8 * u + e] - m) * rstd);
      const int cu = 4 * q + u;
      zt8[p * 16 + (cu ^ (p & 7))] = pk.s;
    }
  }
  __syncthreads();
  const int lane = t & 63, wid = t >> 6;
  const int wr = wid >> 1, wc = wid & 1;
  const int ln = lane & 15, lq = lane >> 4;
  f4v acc[2][2] = {};
#pragma unroll
  for (int kk = 0; kk < 4; ++kk) {
    const int sl = (lq + 4 * kk) ^ (ln & 7);
    s8v a[2], b[2];
#pragma unroll
    for (int mi = 0; mi < 2; ++mi) a[mi] = zt8[(32 * wr + 16 * mi + ln) * 16 + sl];
#pragma unroll
    for (int ni = 0; ni < 2; ++ni) b[ni] = w2s[(32 * wc + 16 * ni + ln) * 16 + sl];
#pragma unroll
    for (int mi = 0; mi < 2; ++mi)
#pragma unroll
      for (int ni = 0; ni < 2; ++ni) acc[mi][ni] = mfma16(a[mi], b[ni], acc[mi][ni]);
  }
#pragma unroll
  for (int mi = 0; mi < 2; ++mi)
#pragma unroll
    for (int ni = 0; ni < 2; ++ni) {
      const int col = 32 * wc + 16 * ni + ln;
      const int jb = 32 * wr + 16 * mi + 4 * lq;
      U4 o4;
#pragma unroll
      for (int r = 0; r < 4; ++r)
        o4.h[r] = __float2bfloat16(acc[mi][ni][r] + bias2s[col] + betas[jb + r][col & 15]);
      *(uint2*)&obuf[col][jb] = o4.u;
    }
  __syncthreads();
  {
    const int oc = t >> 2, js = (t & 3) * 16;
    bf16* dp = bias_all + (size_t)oc * S * S + (size_t)i * S + j0 + js;
    *(s8v*)dp = *(const s8v*)&obuf[oc][js];
    *(s8v*)(dp + 8) = *(const s8v*)&obuf[oc][js + 8];
  }
}

// ---------------- unified reg-staged GEMM, 64x128 tile, paired via z ----------------
// amode 0: A0 ; 1: sig(A0)*A1 ; 2: silu(A0)*A1 ; 3: flash-combine (opA/mlA/gateA)
struct GemmAArgs {
  const bf16* A0[2]; int lda0[2];
  const bf16* A1[2]; int lda1[2];
  const bf16* Bt[2];
  const float* bias[2];
  void* C[2];
  int K[2]; int N[2]; int nb[2];
  int amode[2]; int outMode[2];
  bf16* vT;   // z0 only: cols [1536,2304) -> vT[n-1536][m]
  const float* opA;   // amode 3: flash partials [2][S][CA]
  const float* mlA;   // amode 3: (m,l) pairs [2][NHEAD][S]
  const bf16* gateA;  // amode 3: gate, ld 3072
};

DEV s8v combineRT(s8v x, s8v y, int amode) {
  U8 ux, uy, rr;
  ux.s = x; uy.s = y;
#pragma unroll
  for (int j = 0; j < 8; ++j) {
    const float fx = __bfloat162float(ux.h[j]);
    const float fy = __bfloat162float(uy.h[j]);
    const float tt = sigmoidf_(fx);
    rr.h[j] = __float2bfloat16((amode == 2 ? fx * tt : tt) * fy);
  }
  return rr.s;
}

DEV s8v combineFlash(const float* opart, const float* ml, const bf16* gate,
                     int row, int k) {
  const int h = k / DH;
  const float2 m1 = ((const float2*)ml)[(size_t)h * S + row];
  const float2 m2 = ((const float2*)ml)[(size_t)(NHEAD + h) * S + row];
  const float M = fmaxf(m1.x, m2.x);
  const float w1 = __expf(m1.x - M), w2 = __expf(m2.x - M);
  const float inv = 1.0f / (w1 * m1.y + w2 * m2.y);
  const float* o1p = opart + (size_t)row * CA + k;
  const float* o2p = opart + (size_t)S * CA + (size_t)row * CA + k;
  U8 g; g.s = *(const s8v*)(gate + (size_t)row * 3072 + k);
  U8 r;
#pragma unroll
  for (int j = 0; j < 8; ++j) {
    const float v = (w1 * o1p[j] + w2 * o2p[j]) * inv;
    r.h[j] = __float2bfloat16(sigmoidf_(__bfloat162float(g.h[j])) * v);
  }
  return r.s;
}

__global__ __launch_bounds__(256) void gemmA(GemmAArgs ga) {
  const int z = blockIdx.z;
  if ((int)blockIdx.x >= ga.nb[z]) return;
  __shared__ s8v As[512];
  __shared__ s8v Bs[1024];
  const bf16* A0 = ga.A0[z]; const int lda0 = ga.lda0[z];
  const bf16* A1 = ga.A1[z]; const int lda1 = ga.lda1[z];
  const bf16* Bt = ga.Bt[z];
  const float* bias = ga.bias[z];
  const int K = ga.K[z], N = ga.N[z], amode = ga.amode[z], om = ga.outMode[z];
  const int t = threadIdx.x;
  const int lane = t & 63, wid = t >> 6;
  const int wr = wid >> 1, wc = wid & 1;
  const int ln = lane & 15, lq = lane >> 4;
  const int m0 = blockIdx.y * 64, n0 = blockIdx.x * 128;
  int rowA[2], slA[2], swzA[2];
#pragma unroll
  for (int q = 0; q < 2; ++q) {
    const int u = q * 256 + t;
    rowA[q] = u >> 3; slA[q] = u & 7;
    swzA[q] = rowA[q] * 8 + (slA[q] ^ (rowA[q] & 7));
  }
  int rowB[4], slB[4], swzB[4];
#pragma unroll
  for (int q = 0; q < 4; ++q) {
    const int u = q * 256 + t;
    rowB[q] = u >> 3; slB[q] = u & 7;
    swzB[q] = rowB[q] * 8 + (slB[q] ^ (rowB[q] & 7));
  }
  f4v acc[2][4] = {};
  s8v ra[2], ra2[2], rb[4];
  if (amode != 3) {
#pragma unroll
    for (int q = 0; q < 2; ++q) {
      ra[q] = *(const s8v*)(A0 + (size_t)(m0 + rowA[q]) * lda0 + slA[q] * 8);
      if (amode != 0) ra2[q] = *(const s8v*)(A1 + (size_t)(m0 + rowA[q]) * lda1 + slA[q] * 8);
    }
  }
#pragma unroll
  for (int q = 0; q < 4; ++q)
    rb[q] = *(const s8v*)(Bt + (size_t)(n0 + rowB[q]) * K + slB[q] * 8);
  for (int ks = 0;;) {
    __syncthreads();
    if (amode == 3) {
#pragma unroll
      for (int q = 0; q < 2; ++q)
        As[swzA[q]] = combineFlash(ga.opA, ga.mlA, ga.gateA, m0 + rowA[q], ks + slA[q] * 8);
    } else {
#pragma unroll
      for (int q = 0; q < 2; ++q)
        As[swzA[q]] = (amode == 0) ? ra[q] : combineRT(ra[q], ra2[q], amode);
    }
#pragma unroll
    for (int q = 0; q < 4; ++q) Bs[swzB[q]] = rb[q];
    const int ksn = ks + 64;
    if (ksn < K) {
      if (amode != 3) {
#pragma unroll
        for (int q = 0; q < 2; ++q) {
          ra[q] = *(const s8v*)(A0 + (size_t)(m0 + rowA[q]) * lda0 + ksn + slA[q] * 8);
          if (amode != 0) ra2[q] = *(const s8v*)(A1 + (size_t)(m0 + rowA[q]) * lda1 + ksn + slA[q] * 8);
        }
      }
#pragma unroll
      for (int q = 0; q < 4; ++q)
        rb[q] = *(const s8v*)(Bt + (size_t)(n0 + rowB[q]) * K + ksn + slB[q] * 8);
    }
    __syncthreads();
#pragma unroll
    for (int kk = 0; kk < 2; ++kk) {
      const int sl = (lq + 4 * kk) ^ (ln & 7);
      s8v a[2], b[4];
#pragma unroll
      for (int mi = 0; mi < 2; ++mi) a[mi] = As[(32 * wr + 16 * mi + ln) * 8 + sl];
#pragma unroll
      for (int ni = 0; ni < 4; ++ni) b[ni] = Bs[(64 * wc + 16 * ni + ln) * 8 + sl];
#pragma unroll
      for (int mi = 0; mi < 2; ++mi)
#pragma unroll
        for (int ni = 0; ni < 4; ++ni) acc[mi][ni] = mfma16(a[mi], b[ni], acc[mi][ni]);
    }
    ks = ksn;
    if (ks >= K) break;
  }
  const bool vdiv = (ga.vT != nullptr) && (z == 0) && (n0 >= 1536) && (n0 < 2304);
#pragma unroll
  for (int ni = 0; ni < 4; ++ni) {
    const int n = n0 + 64 * wc + 16 * ni + ln;
    const float bv = bias ? bias[n] : 0.f;
#pragma unroll
    for (int mi = 0; mi < 2; ++mi) {
      const int mb = m0 + 32 * wr + 16 * mi + 4 * lq;
      if (vdiv) {
        U4 o4;
#pragma unroll
        for (int r = 0; r < 4; ++r) o4.h[r] = __float2bfloat16(acc[mi][ni][r] + bv);
        *(uint2*)(ga.vT + (size_t)(n - 1536) * S + mb) = o4.u;
      } else if (om == 0) {
        bf16* Cb = (bf16*)ga.C[z];
#pragma unroll
        for (int r = 0; r < 4; ++r)
          Cb[(size_t)(mb + r) * N + n] = __float2bfloat16(acc[mi][ni][r] + bv);
      } else {
        float* Cf = (float*)ga.C[z];
#pragma unroll
        for (int r = 0; r < 4; ++r)
          Cf[(size_t)(mb + r) * N + n] = sigmoidf_(acc[mi][ni][r] + bv);
      }
    }
  }
}

// ---------------- flash attention, j-split x2 + setprio ----------------
__global__ __launch_bounds__(256) void flash_split(const bf16* __restrict__ qkvg,
                                                   const bf16* __restrict__ vT,
                                                   const bf16* __restrict__ bias_all,
                                                   float* __restrict__ opart,
                                                   float* __restrict__ ml, int blk) {
  __shared__ s8v Qs[64 * 8];
  __shared__ s8v Ks[2][64 * 8];
  __shared__ s8v Vs[2][48 * 8];
  __shared__ s8v Bs[2][64 * 8];
  __shared__ bf16 PwB[4 * 1024];
  __shared__ float facL[4][16];
  const int t = threadIdx.x;
  const int lane = t & 63, w = t >> 6;
  const int ln = lane & 15, lq = lane >> 4;
  const int h = blockIdx.y, i0 = blockIdx.x * 64, half = blockIdx.z;
  const bf16* bp = bias_all + (size_t)(blk * NHEAD + h) * S * S;
  const float scale = 0.14433756729740643f;

#pragma unroll
  for (int uu = 0; uu < 2; ++uu) {
    const int u = t + 256 * uu, row = u >> 3, sl = u & 7;
    s8v qv{};
    if (sl < 6) qv = *(const s8v*)(qkvg + (size_t)(i0 + row) * 3072 + h * DH + sl * 8);
    Qs[row * 8 + (sl ^ (row & 7))] = qv;
  }

  s8v kr[2], br[2], vr0{}, vr1{};
  auto prefetch = [&](int jt) {
    const int j0 = jt * 64;
#pragma unroll
    for (int uu = 0; uu < 2; ++uu) {
      const int u = t + 256 * uu, row = u >> 3, sl = u & 7;
      s8v kv{};
      if (sl < 6) kv = *(const s8v*)(qkvg + (size_t)(j0 + row) * 3072 + 768 + h * DH + sl * 8);
      kr[uu] = kv;
      br[uu] = *(const s8v*)(bp + (size_t)(i0 + row) * S + j0 + sl * 8);
    }
    { const int d = t >> 3, sl = t & 7;
      vr0 = *(const s8v*)(vT + (size_t)(h * DH + d) * S + j0 + sl * 8); }
    if (t < 128) {
      const int u = 256 + t, d = u >> 3, sl = u & 7;
      vr1 = *(const s8v*)(vT + (size_t)(h * DH + d) * S + j0 + sl * 8);
    }
  };
  auto store_tiles = [&](int pb) {
#pragma unroll
    for (int uu = 0; uu < 2; ++uu) {
      const int u = t + 256 * uu, row = u >> 3, sl = u & 7;
      const int ph = row * 8 + (sl ^ (row & 7));
      Ks[pb][ph] = kr[uu];
      Bs[pb][ph] = br[uu];
    }
    { const int d = t >> 3, sl = t & 7;
      Vs[pb][d * 8 + (sl ^ (d & 7))] = vr0; }
    if (t < 128) {
      const int u = 256 + t, d = u >> 3, sl = u & 7;
      Vs[pb][d * 8 + (sl ^ (d & 7))] = vr1;
    }
  };

  float m_run = -3e30f, l_run = 0.f;
  f4v acc_o[3] = {};
  bf16* pw = PwB + w * 1024;

  prefetch(half * 8);
  for (int jt2 = 0; jt2 < 8; ++jt2) {
    const int pb = jt2 & 1;
    __syncthreads();
    store_tiles(pb);
    __syncthreads();
    if (jt2 < 7) prefetch(half * 8 + jt2 + 1);
    float p[4][4];
    float tmax = -3e30f;
    __builtin_amdgcn_s_setprio(1);
#pragma unroll
    for (int ja = 0; ja < 4; ++ja) {
      f4v accs = {};
#pragma unroll
      for (int ks2 = 0; ks2 < 2; ++ks2) {
        const int sl = (lq + 4 * ks2) ^ (ln & 7);
        const s8v a = Ks[pb][(16 * ja + ln) * 8 + sl];
        const s8v b = Qs[(16 * w + ln) * 8 + sl];
        accs = mfma16(a, b, accs);
      }
      const int jq = 4 * ja + lq;
      const int pu = jq >> 1;
      U4 bv;
      bv.u = *(const uint2*)((const bf16*)(&Bs[pb][0]) +
                             (((16 * w + ln) * 8 + (pu ^ (ln & 7))) * 8 + (jq & 1) * 4));
#pragma unroll
      for (int r = 0; r < 4; ++r) {
        p[ja][r] = accs[r] * scale + __bfloat162float(bv.h[r]);
        tmax = fmaxf(tmax, p[ja][r]);
      }
    }
    __builtin_amdgcn_s_setprio(0);
    tmax = fmaxf(tmax, __shfl_xor(tmax, 16));
    tmax = fmaxf(tmax, __shfl_xor(tmax, 32));
    const float m_new = fmaxf(m_run, tmax);
    const float fac = __expf(m_run - m_new);
    m_run = m_new;
    float psum = 0.f;
#pragma unroll
    for (int ja = 0; ja < 4; ++ja)
#pragma unroll
      for (int r = 0; r < 4; ++r) {
        p[ja][r] = __expf(p[ja][r] - m_new);
        psum += p[ja][r];
      }
    psum += __shfl_xor(psum, 16);
    psum += __shfl_xor(psum, 32);
    l_run = l_run * fac + psum;
    if (lq == 0) facL[w][ln] = fac;
#pragma unroll
    for (int ja = 0; ja < 4; ++ja) {
      const int ju = 4 * ja + lq;
      const int ph = ju ^ ((ln & 7) << 1);
      U4 pk;
#pragma unroll
      for (int r = 0; r < 4; ++r) pk.h[r] = __float2bfloat16(p[ja][r]);
      *(uint2*)(pw + ln * 64 + ph * 4) = pk.u;
    }
    asm volatile("s_waitcnt lgkmcnt(0)" ::: "memory");
    __builtin_amdgcn_sched_barrier(0);
    const float4 fv = *(const float4*)&facL[w][4 * lq];
#pragma unroll
    for (int ni = 0; ni < 3; ++ni) {
      acc_o[ni][0] *= fv.x; acc_o[ni][1] *= fv.y;
      acc_o[ni][2] *= fv.z; acc_o[ni][3] *= fv.w;
    }
    __builtin_amdgcn_s_setprio(1);
#pragma unroll
    for (int ks2 = 0; ks2 < 2; ++ks2) {
      const int pu0 = (2 * lq + 8 * ks2) ^ ((ln & 7) << 1);
      const s8v pa = *(const s8v*)(pw + ln * 64 + pu0 * 4);
      const int slv = (lq + 4 * ks2) ^ (ln & 7);
#pragma unroll
      for (int ni = 0; ni < 3; ++ni) {
        const s8v vb = Vs[pb][(16 * ni + ln) * 8 + slv];
        acc_o[ni] = mfma16(pa, vb, acc_o[ni]);
      }
    }
    __builtin_amdgcn_s_setprio(0);
  }
  if (lq == 0) {
    ((float2*)ml)[(size_t)(half * NHEAD + h) * S + i0 + 16 * w + ln] =
        make_float2(m_run, l_run);
  }
  float* op = opart + (size_t)half * S * CA;
#pragma unroll
  for (int ni = 0; ni < 3; ++ni)
#pragma unroll
    for (int r = 0; r < 4; ++r) {
      const int m = i0 + 16 * w + 4 * lq + r;
      op[(size_t)m * CA + h * DH + 16 * ni + ln] = acc_o[ni][r];
    }
}

__global__ void fill_kernel(float* p, int n, float v) {
  const int i = blockIdx.x * 256 + threadIdx.x;
  if (i < n) p[i] = v;
}

extern "C" void kernel_launch(void* const* d_in, const int* in_sizes, int n_in,
                              void* d_out, int out_size, void* d_ws, size_t ws_size,
                              hipStream_t stream) {
  (void)in_sizes; (void)n_in;
  const float* a_in = (const float*)d_in[0];
  const float* s_in = (const float*)d_in[1];
  const float* z_in = (const float*)d_in[2];
  const float* beta = (const float*)d_in[3];
  const float* ln_s_w_attn = (const float*)d_in[4];
  const float* wg_attn = (const float*)d_in[5];
  const float* wb_attn = (const float*)d_in[6];
  const float* wq = (const float*)d_in[7];
  const float* bq = (const float*)d_in[8];
  const float* wk = (const float*)d_in[9];
  const float* wv = (const float*)d_in[10];
  const float* ln_z_w = (const float*)d_in[11];
  const float* ln_z_b = (const float*)d_in[12];
  const float* wpb = (const float*)d_in[13];
  const float* wgate = (const float*)d_in[14];
  const float* wo = (const float*)d_in[15];
  const float* wsg_attn = (const float*)d_in[16];
  const float* bsg_attn = (const float*)d_in[17];
  const float* ln_s_w_tr = (const float*)d_in[18];
  const float* wg_tr = (const float*)d_in[19];
  const float* wb_tr = (const float*)d_in[20];
  const float* w_swish = (const float*)d_in[21];
  const float* w_gate2 = (const float*)d_in[22];
  const float* wsg_tr = (const float*)d_in[23];
  const float* bsg_tr = (const float*)d_in[24];
  const float* w_out = (const float*)d_in[25];

  char* wp = (char*)d_ws;
  size_t used = 0;
  auto alloc = [&](size_t bytes) -> void* {
    void* p = wp + used;
    used += (bytes + 255) & ~(size_t)255;
    return p;
  };
  bf16* bias_all = (bf16*)alloc((size_t)64 * S * S * 2);
  bf16* WT_ada = (bf16*)alloc((size_t)4 * 3072 * 384 * 2);
  bf16* WT_sg = (bf16*)alloc((size_t)4 * 1536 * 384 * 2);
  bf16* WT_qkvg = (bf16*)alloc((size_t)4 * 3072 * 768 * 2);
  bf16* WT_wo = (bf16*)alloc((size_t)4 * 768 * 768 * 2);
  bf16* WT_mlp = (bf16*)alloc((size_t)4 * 3072 * 768 * 2);
  bf16* WT_wout = (bf16*)alloc((size_t)4 * 768 * 1536 * 2);
  float* biasQKVG = (float*)alloc(4 * 3072 * 4);
  float* biasSG = (float*)alloc(6144 * 4);
  bf16* W2T = (bf16*)alloc(64 * 128 * 2);
  float* bias2 = (float*)alloc(64 * 4);
  bf16* ada_all = (bf16*)alloc((size_t)S * 12288 * 2);
  float* sg_all = (float*)alloc((size_t)S * 6144 * 4);
  bf16* s_hat = (bf16*)alloc((size_t)S * CS * 2);
  bf16* s_bf = (bf16*)alloc((size_t)S * CS * 2);
  bf16* ah_attn = (bf16*)alloc((size_t)S * CA * 2);
  bf16* ah_tr = (bf16*)alloc((size_t)S * CA * 2);
  bf16* qkvg = (bf16*)alloc((size_t)S * 3072 * 2);
  bf16* vT = (bf16*)alloc((size_t)CA * S * 2);
  bf16* att = (bf16*)alloc((size_t)S * CA * 2);
  bf16* swg = (bf16*)alloc((size_t)S * 3072 * 2);
  bf16* trout = (bf16*)alloc((size_t)S * CA * 2);
  float* opart = (float*)alloc((size_t)2 * S * CA * 4);
  float* ml = (float*)alloc((size_t)2 * NHEAD * S * 8);
  if (used > ws_size) {
    fill_kernel<<<(out_size + 255) / 256, 256, 0, stream>>>((float*)d_out, out_size, 12345.0f);
    return;
  }

  const dim3 B256(256);

  {  // launch 1: all prep (transposes + biases + s-LN)
    PrepFatArgs pa{};
    pa.tsrc[0] = wg_attn;  pa.tdst[0] = WT_ada + (size_t)0 * 384;    pa.tcs[0] = ln_s_w_attn; pa.tdstZ[0] = 3072 * 384;
    pa.tsrc[1] = wb_attn;  pa.tdst[1] = WT_ada + (size_t)768 * 384;  pa.tcs[1] = ln_s_w_attn; pa.tdstZ[1] = 3072 * 384;
    pa.tsrc[2] = wg_tr;    pa.tdst[2] = WT_ada + (size_t)1536 * 384; pa.tcs[2] = ln_s_w_tr;   pa.tdstZ[2] = 3072 * 384;
    pa.tsrc[3] = wb_tr;    pa.tdst[3] = WT_ada + (size_t)2304 * 384; pa.tcs[3] = ln_s_w_tr;   pa.tdstZ[3] = 3072 * 384;
    pa.tsrc[4] = wsg_attn; pa.tdst[4] = WT_sg + (size_t)0 * 384;     pa.tcs[4] = nullptr;     pa.tdstZ[4] = 1536 * 384;
    pa.tsrc[5] = wsg_tr;   pa.tdst[5] = WT_sg + (size_t)768 * 384;   pa.tcs[5] = nullptr;     pa.tdstZ[5] = 1536 * 384;
    pa.tsrc[6] = wq;    pa.tdst[6] = WT_qkvg + (size_t)0 * 768;    pa.tdstZ[6] = 3072 * 768;
    pa.tsrc[7] = wk;    pa.tdst[7] = WT_qkvg + (size_t)768 * 768;  pa.tdstZ[7] = 3072 * 768;
    pa.tsrc[8] = wv;    pa.tdst[8] = WT_qkvg + (size_t)1536 * 768; pa.tdstZ[8] = 3072 * 768;
    pa.tsrc[9] = wgate; pa.tdst[9] = WT_qkvg + (size_t)2304 * 768; pa.tdstZ[9] = 3072 * 768;
    pa.tsrc[10] = wo;   pa.tdst[10] = WT_wo;                       pa.tdstZ[10] = 768 * 768;
    pa.tsrc[11] = w_swish; pa.tdst[11] = WT_mlp + (size_t)0 * 768;    pa.tdstZ[11] = 3072 * 768;
    pa.tsrc[12] = w_gate2; pa.tdst[12] = WT_mlp + (size_t)1536 * 768; pa.tdstZ[12] = 3072 * 768;
    pa.tsrc[13] = w_out; pa.tdst[13] = WT_wout; pa.tdstZ[13] = 768 * 1536;
    pa.ln_z_w = ln_z_w; pa.ln_z_b = ln_z_b; pa.wpb = wpb;
    pa.bq = bq; pa.bsg_a = bsg_attn; pa.bsg_t = bsg_tr;
    pa.W2T = W2T; pa.bias2 = bias2; pa.biasQKVG = biasQKVG; pa.biasSG = biasSG;
    pa.s_in = s_in; pa.s_hat = s_hat; pa.s_bf = s_bf;
    prep_fat<<<33329, B256, 0, stream>>>(pa);
  }

  zbias_kernel<<<dim3(16, 1024), B256, 0, stream>>>(z_in, beta, W2T, bias2, bias_all);

  {  // hoisted: z0 ada (N=12288), z1 sg (N=6144, f32+sigmoid)
    GemmAArgs ga{};
    ga.A0[0] = s_hat; ga.lda0[0] = 384; ga.Bt[0] = WT_ada; ga.bias[0] = nullptr;
    ga.C[0] = ada_all; ga.K[0] = 384; ga.N[0] = 12288; ga.nb[0] = 96;
    ga.amode[0] = 0; ga.outMode[0] = 0;
    ga.A0[1] = s_bf; ga.lda0[1] = 384; ga.Bt[1] = WT_sg; ga.bias[1] = biasSG;
    ga.C[1] = sg_all; ga.K[1] = 384; ga.N[1] = 6144; ga.nb[1] = 48;
    ga.amode[1] = 0; ga.outMode[1] = 1;
    ga.vT = nullptr;
    gemmA<<<dim3(96, 16, 2), B256, 0, stream>>>(ga);
  }

  ln_adaln2<<<S, B256, 0, stream>>>(a_in, ada_all, ah_attn, ah_tr);
  for (int b = 0; b < NBLK; ++b) {
    {  // z0 qkvg (with vT divert), z1 mlp(swg)
      GemmAArgs ga{};
      ga.A0[0] = ah_attn; ga.lda0[0] = 768; ga.Bt[0] = WT_qkvg + (size_t)b * 3072 * 768;
      ga.bias[0] = biasQKVG + b * 3072; ga.C[0] = qkvg; ga.K[0] = 768; ga.N[0] = 3072;
      ga.nb[0] = 24; ga.amode[0] = 0; ga.outMode[0] = 0;
      ga.A0[1] = ah_tr; ga.lda0[1] = 768; ga.Bt[1] = WT_mlp + (size_t)b * 3072 * 768;
      ga.bias[1] = nullptr; ga.C[1] = swg; ga.K[1] = 768; ga.N[1] = 3072;
      ga.nb[1] = 24; ga.amode[1] = 0; ga.outMode[1] = 0;
      ga.vT = vT;
      gemmA<<<dim3(24, 16, 2), B256, 0, stream>>>(ga);
    }
    flash_split<<<dim3(16, 16, 2), B256, 0, stream>>>(qkvg, vT, bias_all, opart, ml, b);
    {  // z0 att = combineFlash(opart,ml,gate)@wo ; z1 trout = swiglu(swg)@w_out
      GemmAArgs ga{};
      ga.A0[0] = nullptr; ga.lda0[0] = 0;
      ga.Bt[0] = WT_wo + (size_t)b * 768 * 768; ga.bias[0] = nullptr;
      ga.C[0] = att; ga.K[0] = 768; ga.N[0] = 768; ga.nb[0] = 6;
      ga.amode[0] = 3; ga.outMode[0] = 0;
      ga.A0[1] = swg; ga.lda0[1] = 3072; ga.A1[1] = swg + 1536; ga.lda1[1] = 3072;
      ga.Bt[1] = WT_wout + (size_t)b * 768 * 1536; ga.bias[1] = nullptr;
      ga.C[1] = trout; ga.K[1] = 1536; ga.N[1] = 768; ga.nb[1] = 6;
      ga.amode[1] = 2; ga.outMode[1] = 0;
      ga.vT = nullptr;
      ga.opA = opart; ga.mlA = ml; ga.gateA = qkvg + 2304;
      gemmA<<<dim3(6, 16, 2), B256, 0, stream>>>(ga);
    }
    if (b < NBLK - 1) {
      final_adaln<<<S, B256, 0, stream>>>(sg_all + (size_t)b * 1536, att, trout,
                                          ada_all + (size_t)(b + 1) * 3072, ah_attn, ah_tr);
    } else {
      ew_final<<<768, B256, 0, stream>>>(sg_all + (size_t)b * 1536, att, trout, (float*)d_out);
    }
  }
}